// Round 1
// baseline (390.304 us; speedup 1.0000x reference)
//
#include <hip/hip_runtime.h>
#include <hip/hip_bf16.h>
#include <cstdint>
#include <cstddef>

// Problem constants (fixed by the reference):
#define TTOK 4096
#define DM   1024
#define NE   8
#define KTOP 2
#define FFD  1024
#define CPER 1024   // TTOK*KTOP/NE tokens per expert (balanced)

typedef __attribute__((ext_vector_type(8))) short frag8;   // 8 bf16 = 4 VGPRs
typedef __attribute__((ext_vector_type(4))) float f32x4;   // MFMA accumulator

static __device__ __forceinline__ unsigned short f2bf(float f) {
  unsigned int u = __float_as_uint(f);
  u += 0x7fff + ((u >> 16) & 1);     // round-to-nearest-even
  return (unsigned short)(u >> 16);
}

static __device__ __forceinline__ void gld_lds16(const unsigned short* g, unsigned short* l) {
  __builtin_amdgcn_global_load_lds(
      (const __attribute__((address_space(1))) unsigned int*)g,
      (__attribute__((address_space(3))) unsigned int*)l,
      16, 0, 0);
}

// Stage a 128x32 bf16 tile (row stride 1024 elems) into LDS, linear layout
// [128][32] (required by global_load_lds: wave-uniform base + lane*16B).
static __device__ __forceinline__ void stage_tile(const unsigned short* __restrict__ src,
                                                  int row0, int k0,
                                                  unsigned short* lds, int tid) {
#pragma unroll
  for (int it = 0; it < 2; ++it) {
    int seg = it * 256 + tid;        // 512 segments of 16B
    int r = seg >> 2;                // tile row
    int cs = seg & 3;                // 8-elem column segment
    gld_lds16(src + (size_t)(row0 + r) * 1024 + k0 + cs * 8, lds + seg * 8);
  }
}

// ---------------- permutation / routing ----------------
__global__ void perm_kernel(const int* __restrict__ idx, const float* __restrict__ tw,
                            int* __restrict__ cnt, int* __restrict__ rowdst,
                            float* __restrict__ rowscale) {
  int i = blockIdx.x * 256 + threadIdx.x;        // i < TTOK*KTOP
  int e = idx[i];
  int pos = atomicAdd(&cnt[e], 1);               // order within expert is irrelevant
  int j = e * CPER + pos;
  rowdst[j] = i >> 1;                            // token id (KTOP==2)
  rowscale[j] = tw[i];
}

// ---------------- fp32 -> bf16 convert (shared-expert input) ----------------
__global__ void convx_kernel(const float* __restrict__ x, unsigned short* __restrict__ xb) {
  int i = blockIdx.x * 256 + threadIdx.x;        // i < TTOK*DM/4
  float4 v = ((const float4*)x)[i];
  ushort4 o;
  o.x = f2bf(v.x); o.y = f2bf(v.y); o.z = f2bf(v.z); o.w = f2bf(v.w);
  ((ushort4*)xb)[i] = o;
}

// ---------------- gather permuted rows + cast ----------------
__global__ void gather_kernel(const float* __restrict__ x, const int* __restrict__ rowdst,
                              unsigned short* __restrict__ xp) {
  int j = blockIdx.x;                            // permuted row
  int t = rowdst[j];
  int c = threadIdx.x;                           // 256 threads * float4 = 1024 elems
  float4 v = ((const float4*)(x + (size_t)t * 1024))[c];
  ushort4 o;
  o.x = f2bf(v.x); o.y = f2bf(v.y); o.z = f2bf(v.z); o.w = f2bf(v.w);
  ((ushort4*)(xp + (size_t)j * 1024))[c] = o;
}

// ---------------- transpose + cast all 27 1024x1024 weight mats ----------------
__global__ void transw_kernel(const float* __restrict__ wg, const float* __restrict__ wu,
                              const float* __restrict__ wd, const float* __restrict__ sg,
                              const float* __restrict__ su, const float* __restrict__ sd,
                              unsigned short* __restrict__ owg, unsigned short* __restrict__ owu,
                              unsigned short* __restrict__ owd, unsigned short* __restrict__ osg,
                              unsigned short* __restrict__ osu, unsigned short* __restrict__ osd) {
  int z = blockIdx.z;
  const float* src; unsigned short* dst;
  if (z < 8)       { src = wg + (size_t)z * 1048576;        dst = owg + (size_t)z * 1048576; }
  else if (z < 16) { src = wu + (size_t)(z - 8) * 1048576;  dst = owu + (size_t)(z - 8) * 1048576; }
  else if (z < 24) { src = wd + (size_t)(z - 16) * 1048576; dst = owd + (size_t)(z - 16) * 1048576; }
  else if (z == 24){ src = sg; dst = osg; }
  else if (z == 25){ src = su; dst = osu; }
  else             { src = sd; dst = osd; }
  __shared__ float tile[32][33];
  int bx = blockIdx.x * 32;   // src col base
  int by = blockIdx.y * 32;   // src row base
  int tx = threadIdx.x, ty = threadIdx.y;
#pragma unroll
  for (int i = 0; i < 4; ++i)
    tile[ty + 8 * i][tx] = src[(size_t)(by + ty + 8 * i) * 1024 + bx + tx];
  __syncthreads();
#pragma unroll
  for (int i = 0; i < 4; ++i)
    dst[(size_t)(bx + ty + 8 * i) * 1024 + by + tx] = f2bf(tile[tx][ty + 8 * i]);
}

// ---------------- shared-expert sigmoid gate ----------------
__global__ void gate_kernel(const float* __restrict__ x, const float* __restrict__ gw,
                            float* __restrict__ g) {
  int t = blockIdx.x * 4 + (threadIdx.x >> 6);   // 4 waves = 4 tokens per block
  int lane = threadIdx.x & 63;
  const float4* xr = (const float4*)(x + (size_t)t * 1024);
  const float4* wr = (const float4*)gw;
  float s = 0.f;
#pragma unroll
  for (int c = lane; c < 256; c += 64) {
    float4 a = xr[c], b = wr[c];
    s += a.x * b.x + a.y * b.y + a.z * b.z + a.w * b.w;
  }
#pragma unroll
  for (int off = 32; off; off >>= 1) s += __shfl_down(s, off);
  if (lane == 0) g[t] = 1.f / (1.f + __expf(-s));
}

// ---------------- GEMM1: H = silu(A @ Wg) * (A @ Wu), bf16 out ----------------
// A: [Mtot][1024] bf16; Bg/Bu: [E][1024][1024] bf16, N-major (pre-transposed).
// grid (N/128, Crows/128, E), block 256.
__global__ __launch_bounds__(256, 2) void gemm1_kernel(
    const unsigned short* __restrict__ A, const unsigned short* __restrict__ Bg,
    const unsigned short* __restrict__ Bu, unsigned short* __restrict__ H, int Crows) {
  __shared__ __align__(16) unsigned short As[128 * 32];
  __shared__ __align__(16) unsigned short Bgs[128 * 32];
  __shared__ __align__(16) unsigned short Bus[128 * 32];
  int tid = threadIdx.x;
  int e = blockIdx.z;
  int row0 = e * Crows + blockIdx.y * 128;
  int col0 = blockIdx.x * 128;
  const unsigned short* Bge = Bg + (size_t)e * 1048576;
  const unsigned short* Bue = Bu + (size_t)e * 1048576;

  int wave = tid >> 6, lane = tid & 63;
  int wm = wave >> 1, wn = wave & 1;             // 2x2 wave grid, 64x64 per wave
  int lr = lane & 15, q = lane >> 4;

  f32x4 accg[4][4], accu[4][4];
#pragma unroll
  for (int i = 0; i < 4; ++i)
#pragma unroll
    for (int j = 0; j < 4; ++j) {
      accg[i][j] = (f32x4){0.f, 0.f, 0.f, 0.f};
      accu[i][j] = (f32x4){0.f, 0.f, 0.f, 0.f};
    }

  for (int kt = 0; kt < 1024; kt += 32) {
    stage_tile(A, row0, kt, As, tid);
    stage_tile(Bge, col0, kt, Bgs, tid);
    stage_tile(Bue, col0, kt, Bus, tid);
    __syncthreads();                             // drains vmcnt for global_load_lds
    frag8 a[4], b0[4], b1[4];
#pragma unroll
    for (int i = 0; i < 4; ++i)
      a[i] = *(const frag8*)&As[(wm * 64 + i * 16 + lr) * 32 + q * 8];
#pragma unroll
    for (int j = 0; j < 4; ++j) {
      b0[j] = *(const frag8*)&Bgs[(wn * 64 + j * 16 + lr) * 32 + q * 8];
      b1[j] = *(const frag8*)&Bus[(wn * 64 + j * 16 + lr) * 32 + q * 8];
    }
#pragma unroll
    for (int i = 0; i < 4; ++i)
#pragma unroll
      for (int j = 0; j < 4; ++j) {
        accg[i][j] = __builtin_amdgcn_mfma_f32_16x16x32_bf16(a[i], b0[j], accg[i][j], 0, 0, 0);
        accu[i][j] = __builtin_amdgcn_mfma_f32_16x16x32_bf16(a[i], b1[j], accu[i][j], 0, 0, 0);
      }
    __syncthreads();
  }
#pragma unroll
  for (int i = 0; i < 4; ++i)
#pragma unroll
    for (int j = 0; j < 4; ++j)
#pragma unroll
      for (int r = 0; r < 4; ++r) {
        int m = row0 + wm * 64 + i * 16 + q * 4 + r;   // C/D: row=quad*4+reg
        int n = col0 + wn * 64 + j * 16 + lr;          //       col=lane&15
        float gv = accg[i][j][r];
        float hv = gv / (1.f + __expf(-gv)) * accu[i][j][r];
        H[(size_t)m * 1024 + n] = f2bf(hv);
      }
}

// ---------------- GEMM2: out[t] += scale * (A @ Wd) ----------------
__global__ __launch_bounds__(256, 2) void gemm2_kernel(
    const unsigned short* __restrict__ A, const unsigned short* __restrict__ B,
    const int* __restrict__ rowdst, const float* __restrict__ rowscale,
    float* __restrict__ out, int Crows) {
  __shared__ __align__(16) unsigned short As[128 * 32];
  __shared__ __align__(16) unsigned short Bs[128 * 32];
  int tid = threadIdx.x;
  int e = blockIdx.z;
  int row0 = e * Crows + blockIdx.y * 128;
  int col0 = blockIdx.x * 128;
  const unsigned short* Be = B + (size_t)e * 1048576;

  int wave = tid >> 6, lane = tid & 63;
  int wm = wave >> 1, wn = wave & 1;
  int lr = lane & 15, q = lane >> 4;

  f32x4 acc[4][4];
#pragma unroll
  for (int i = 0; i < 4; ++i)
#pragma unroll
    for (int j = 0; j < 4; ++j) acc[i][j] = (f32x4){0.f, 0.f, 0.f, 0.f};

  for (int kt = 0; kt < 1024; kt += 32) {
    stage_tile(A, row0, kt, As, tid);
    stage_tile(Be, col0, kt, Bs, tid);
    __syncthreads();
    frag8 a[4], b[4];
#pragma unroll
    for (int i = 0; i < 4; ++i)
      a[i] = *(const frag8*)&As[(wm * 64 + i * 16 + lr) * 32 + q * 8];
#pragma unroll
    for (int j = 0; j < 4; ++j)
      b[j] = *(const frag8*)&Bs[(wn * 64 + j * 16 + lr) * 32 + q * 8];
#pragma unroll
    for (int i = 0; i < 4; ++i)
#pragma unroll
      for (int j = 0; j < 4; ++j)
        acc[i][j] = __builtin_amdgcn_mfma_f32_16x16x32_bf16(a[i], b[j], acc[i][j], 0, 0, 0);
    __syncthreads();
  }
  int n_base = col0 + wn * 64;
#pragma unroll
  for (int i = 0; i < 4; ++i)
#pragma unroll
    for (int r = 0; r < 4; ++r) {
      int row = row0 + wm * 64 + i * 16 + q * 4 + r;
      int t = rowdst ? rowdst[row] : row;
      float sc = rowscale[row];
      float* orow = out + (size_t)t * 1024 + n_base;
#pragma unroll
      for (int j = 0; j < 4; ++j)
        atomicAdd(&orow[j * 16 + lr], acc[i][j][r] * sc);
    }
}

extern "C" void kernel_launch(void* const* d_in, const int* in_sizes, int n_in,
                              void* d_out, int out_size, void* d_ws, size_t ws_size,
                              hipStream_t stream) {
  (void)in_sizes; (void)n_in; (void)out_size; (void)ws_size;
  const float* hidden  = (const float*)d_in[0];
  const float* topk_w  = (const float*)d_in[1];
  const float* w_gate  = (const float*)d_in[2];
  const float* w_up    = (const float*)d_in[3];
  const float* w_down  = (const float*)d_in[4];
  const float* sw_gate = (const float*)d_in[5];
  const float* sw_up   = (const float*)d_in[6];
  const float* sw_down = (const float*)d_in[7];
  const float* sgw     = (const float*)d_in[8];
  const int*   topk_i  = (const int*)d_in[9];
  float* out = (float*)d_out;

  char* p = (char*)d_ws;
  auto alloc = [&](size_t bytes) {
    char* r = p;
    p += (bytes + 255) & ~(size_t)255;
    return r;
  };
  unsigned short* wg_t  = (unsigned short*)alloc((size_t)NE * 1048576 * 2);
  unsigned short* wu_t  = (unsigned short*)alloc((size_t)NE * 1048576 * 2);
  unsigned short* wd_t  = (unsigned short*)alloc((size_t)NE * 1048576 * 2);
  unsigned short* swg_t = (unsigned short*)alloc((size_t)1048576 * 2);
  unsigned short* swu_t = (unsigned short*)alloc((size_t)1048576 * 2);
  unsigned short* swd_t = (unsigned short*)alloc((size_t)1048576 * 2);
  unsigned short* Xs    = (unsigned short*)alloc((size_t)TTOK * DM * 2);
  unsigned short* Xp    = (unsigned short*)alloc((size_t)TTOK * KTOP * DM * 2);
  unsigned short* H     = (unsigned short*)alloc((size_t)TTOK * KTOP * FFD * 2);
  int*   cnt      = (int*)alloc(NE * 4);
  int*   rowdst   = (int*)alloc((size_t)TTOK * KTOP * 4);
  float* rowscale = (float*)alloc((size_t)TTOK * KTOP * 4);
  float* gbuf     = (float*)alloc((size_t)TTOK * 4);

  hipMemsetAsync(out, 0, (size_t)TTOK * DM * 4, stream);
  hipMemsetAsync(cnt, 0, NE * 4, stream);

  perm_kernel<<<TTOK * KTOP / 256, 256, 0, stream>>>(topk_i, topk_w, cnt, rowdst, rowscale);
  convx_kernel<<<TTOK * DM / 4 / 256, 256, 0, stream>>>(hidden, Xs);
  gather_kernel<<<TTOK * KTOP, 256, 0, stream>>>(hidden, rowdst, Xp);
  transw_kernel<<<dim3(32, 32, 27), dim3(32, 8), 0, stream>>>(
      w_gate, w_up, w_down, sw_gate, sw_up, sw_down,
      wg_t, wu_t, wd_t, swg_t, swu_t, swd_t);
  gate_kernel<<<TTOK / 4, 256, 0, stream>>>(hidden, sgw, gbuf);

  // MoE: H = silu(Xp Wg) * (Xp Wu); out += w * (H Wd)
  gemm1_kernel<<<dim3(8, 8, 8), 256, 0, stream>>>(Xp, wg_t, wu_t, H, CPER);
  gemm2_kernel<<<dim3(8, 8, 8), 256, 0, stream>>>(H, wd_t, rowdst, rowscale, out, CPER);

  // Shared expert: out += g * ((silu(Xs Sg) * (Xs Su)) Sd)
  gemm1_kernel<<<dim3(8, 32, 1), 256, 0, stream>>>(Xs, swg_t, swu_t, H, TTOK);
  gemm2_kernel<<<dim3(8, 32, 1), 256, 0, stream>>>(H, swd_t, (const int*)nullptr, gbuf, out, TTOK);
}

// Round 3
// 333.679 us; speedup vs baseline: 1.1697x; 1.1697x over previous
//
#include <hip/hip_runtime.h>
#include <hip/hip_bf16.h>
#include <cstdint>
#include <cstddef>

// Problem constants (fixed by the reference):
#define TTOK 4096
#define DM   1024
#define NE   8
#define KTOP 2
#define FFD  1024
#define CPER 1024       // TTOK*KTOP/NE tokens per expert (balanced)
#define MROWS 12288     // 8192 MoE permuted rows + 4096 shared rows

typedef __attribute__((ext_vector_type(8))) short frag8;   // 8 bf16 = 4 VGPRs
typedef __attribute__((ext_vector_type(4))) float f32x4;   // MFMA accumulator

static __device__ __forceinline__ unsigned short f2bf(float f) {
  unsigned int u = __float_as_uint(f);
  u += 0x7fff + ((u >> 16) & 1);     // round-to-nearest-even
  return (unsigned short)(u >> 16);
}
static __device__ __forceinline__ float bf2f(unsigned short u) {
  return __uint_as_float((unsigned int)u << 16);
}

static __device__ __forceinline__ void gld_lds16(const unsigned short* g, unsigned short* l) {
  __builtin_amdgcn_global_load_lds(
      (const __attribute__((address_space(1))) unsigned int*)g,
      (__attribute__((address_space(3))) unsigned int*)l,
      16, 0, 0);
}

// LDS bank-conflict swizzle. Tile = 128 rows x 4 segments of 16B.
// global_load_lds forces the LDS write layout to be LINEAR (wave base +
// lane*16B — m104/m108: per-lane LDS pointers are ignored!), so the swizzle
// must be applied on the GLOBAL address side: the lane filling linear slot
// `seg` fetches global segment cs = (seg&3) ^ ((r>>1)&3). XOR is involutive,
// so the reader finds global segment (r,q) at slot lds_slot(r,q).
// Read pattern over 8 consecutive rows then hits start banks
// {0,16,4,20,8,24,12,28} -> all 32 banks per 8 rows, 2-way alias = free (m136).
static __device__ __forceinline__ int lds_slot(int r, int cs) {
  return r * 4 + (cs ^ ((r >> 1) & 3));
}

// Stage a 128x32 bf16 tile (row stride 1024 elems) into LDS (linear write,
// global-side swizzle).
static __device__ __forceinline__ void stage_tile(const unsigned short* __restrict__ src,
                                                  int row0, int k0,
                                                  unsigned short* lds, int tid) {
#pragma unroll
  for (int it = 0; it < 2; ++it) {
    int seg = it * 256 + tid;        // 512 linear 16B slots
    int r = seg >> 2;                // tile row
    int cs = (seg & 3) ^ ((r >> 1) & 3);   // swizzled global column segment
    gld_lds16(src + (size_t)(row0 + r) * 1024 + k0 + cs * 8, lds + seg * 8);
  }
}

// ---------------- permutation / routing ----------------
__global__ void perm_kernel(const int* __restrict__ idx, int* __restrict__ cnt,
                            int* __restrict__ rowdst, int* __restrict__ inv) {
  int i = blockIdx.x * 256 + threadIdx.x;        // i < TTOK*KTOP
  int e = idx[i];
  int pos = atomicAdd(&cnt[e], 1);               // order within expert irrelevant
  int j = e * CPER + pos;
  rowdst[j] = i >> 1;                            // token id (KTOP==2)
  inv[i] = j;                                    // inverse permutation for combine
}

// ---------------- pack activations: [12288][1024] bf16 ----------------
// rows 0..8191: permuted MoE copies; rows 8192..12287: the raw tokens (shared).
__global__ void pack_kernel(const float* __restrict__ x, const int* __restrict__ rowdst,
                            unsigned short* __restrict__ xall) {
  int j = blockIdx.x;
  int t = (j < 8192) ? rowdst[j] : (j - 8192);
  int c = threadIdx.x;                           // 256 threads * float4 = 1024 elems
  float4 v = ((const float4*)(x + (size_t)t * 1024))[c];
  ushort4 o;
  o.x = f2bf(v.x); o.y = f2bf(v.y); o.z = f2bf(v.z); o.w = f2bf(v.w);
  ((ushort4*)(xall + (size_t)j * 1024))[c] = o;
}

// ---------------- transpose + cast all 27 1024x1024 weight mats ----------------
// Outputs packed [9][1024][1024] per matrix kind; index 8 = shared expert.
__global__ void transw_kernel(const float* __restrict__ wg, const float* __restrict__ wu,
                              const float* __restrict__ wd, const float* __restrict__ sg,
                              const float* __restrict__ su, const float* __restrict__ sd,
                              unsigned short* __restrict__ owg, unsigned short* __restrict__ owu,
                              unsigned short* __restrict__ owd) {
  int z = blockIdx.z;
  const float* src; unsigned short* dst;
  if (z < 8)       { src = wg + (size_t)z * 1048576;        dst = owg + (size_t)z * 1048576; }
  else if (z < 16) { src = wu + (size_t)(z - 8) * 1048576;  dst = owu + (size_t)(z - 8) * 1048576; }
  else if (z < 24) { src = wd + (size_t)(z - 16) * 1048576; dst = owd + (size_t)(z - 16) * 1048576; }
  else if (z == 24){ src = sg; dst = owg + (size_t)8 * 1048576; }
  else if (z == 25){ src = su; dst = owu + (size_t)8 * 1048576; }
  else             { src = sd; dst = owd + (size_t)8 * 1048576; }
  __shared__ float tile[32][33];
  int bx = blockIdx.x * 32;   // src col base
  int by = blockIdx.y * 32;   // src row base
  int tx = threadIdx.x, ty = threadIdx.y;
#pragma unroll
  for (int i = 0; i < 4; ++i)
    tile[ty + 8 * i][tx] = src[(size_t)(by + ty + 8 * i) * 1024 + bx + tx];
  __syncthreads();
#pragma unroll
  for (int i = 0; i < 4; ++i)
    dst[(size_t)(bx + ty + 8 * i) * 1024 + by + tx] = f2bf(tile[tx][ty + 8 * i]);
}

// ---------------- shared-expert sigmoid gate ----------------
__global__ void gate_kernel(const float* __restrict__ x, const float* __restrict__ gw,
                            float* __restrict__ g) {
  int t = blockIdx.x * 4 + (threadIdx.x >> 6);   // 4 waves = 4 tokens per block
  int lane = threadIdx.x & 63;
  const float4* xr = (const float4*)(x + (size_t)t * 1024);
  const float4* wr = (const float4*)gw;
  float s = 0.f;
#pragma unroll
  for (int c = lane; c < 256; c += 64) {
    float4 a = xr[c], b = wr[c];
    s += a.x * b.x + a.y * b.y + a.z * b.z + a.w * b.w;
  }
#pragma unroll
  for (int off = 32; off; off >>= 1) s += __shfl_down(s, off);
  if (lane == 0) g[t] = 1.f / (1.f + __expf(-s));
}

// Expert id for a 128-row M-block: y<64 -> MoE expert y/8; else shared (8).
static __device__ __forceinline__ int eid_of(int y) { return (y < 64) ? (y >> 3) : 8; }

// ---------------- GEMM1: H = silu(A @ Wg) * (A @ Wu), bf16 out ----------------
// A: [12288][1024] bf16; Bg/Bu: [9][1024][1024] bf16, N-major (pre-transposed).
// grid (8, 96), block 256.
__global__ __launch_bounds__(256, 2) void gemm1_kernel(
    const unsigned short* __restrict__ A, const unsigned short* __restrict__ Bg,
    const unsigned short* __restrict__ Bu, unsigned short* __restrict__ H) {
  __shared__ __align__(16) unsigned short As[128 * 32];
  __shared__ __align__(16) unsigned short Bgs[128 * 32];
  __shared__ __align__(16) unsigned short Bus[128 * 32];
  int tid = threadIdx.x;
  int e = eid_of(blockIdx.y);
  int row0 = blockIdx.y * 128;
  int col0 = blockIdx.x * 128;
  const unsigned short* Bge = Bg + (size_t)e * 1048576;
  const unsigned short* Bue = Bu + (size_t)e * 1048576;

  int wave = tid >> 6, lane = tid & 63;
  int wm = wave >> 1, wn = wave & 1;             // 2x2 wave grid, 64x64 per wave
  int lr = lane & 15, q = lane >> 4;

  f32x4 accg[4][4], accu[4][4];
#pragma unroll
  for (int i = 0; i < 4; ++i)
#pragma unroll
    for (int j = 0; j < 4; ++j) {
      accg[i][j] = (f32x4){0.f, 0.f, 0.f, 0.f};
      accu[i][j] = (f32x4){0.f, 0.f, 0.f, 0.f};
    }

  for (int kt = 0; kt < 1024; kt += 32) {
    stage_tile(A, row0, kt, As, tid);
    stage_tile(Bge, col0, kt, Bgs, tid);
    stage_tile(Bue, col0, kt, Bus, tid);
    __syncthreads();                             // drains vmcnt for global_load_lds
    frag8 a[4], b0[4], b1[4];
#pragma unroll
    for (int i = 0; i < 4; ++i) {
      int r = wm * 64 + i * 16 + lr;
      a[i] = *(const frag8*)&As[lds_slot(r, q) * 8];
    }
#pragma unroll
    for (int j = 0; j < 4; ++j) {
      int r = wn * 64 + j * 16 + lr;
      b0[j] = *(const frag8*)&Bgs[lds_slot(r, q) * 8];
      b1[j] = *(const frag8*)&Bus[lds_slot(r, q) * 8];
    }
#pragma unroll
    for (int i = 0; i < 4; ++i)
#pragma unroll
      for (int j = 0; j < 4; ++j) {
        accg[i][j] = __builtin_amdgcn_mfma_f32_16x16x32_bf16(a[i], b0[j], accg[i][j], 0, 0, 0);
        accu[i][j] = __builtin_amdgcn_mfma_f32_16x16x32_bf16(a[i], b1[j], accu[i][j], 0, 0, 0);
      }
    __syncthreads();
  }
#pragma unroll
  for (int i = 0; i < 4; ++i)
#pragma unroll
    for (int j = 0; j < 4; ++j)
#pragma unroll
      for (int r = 0; r < 4; ++r) {
        int m = row0 + wm * 64 + i * 16 + q * 4 + r;   // C/D: row=quad*4+reg
        int n = col0 + wn * 64 + j * 16 + lr;          //       col=lane&15
        float gv = accg[i][j][r];
        float hv = gv / (1.f + __expf(-gv)) * accu[i][j][r];
        H[(size_t)m * 1024 + n] = f2bf(hv);
      }
}

// ---------------- GEMM2: Y = A @ Wd, bf16 out (dense, no scatter) ----------------
__global__ __launch_bounds__(256, 2) void gemm2_kernel(
    const unsigned short* __restrict__ A, const unsigned short* __restrict__ B,
    unsigned short* __restrict__ Y) {
  __shared__ __align__(16) unsigned short As[128 * 32];
  __shared__ __align__(16) unsigned short Bs[128 * 32];
  int tid = threadIdx.x;
  int e = eid_of(blockIdx.y);
  int row0 = blockIdx.y * 128;
  int col0 = blockIdx.x * 128;
  const unsigned short* Be = B + (size_t)e * 1048576;

  int wave = tid >> 6, lane = tid & 63;
  int wm = wave >> 1, wn = wave & 1;
  int lr = lane & 15, q = lane >> 4;

  f32x4 acc[4][4];
#pragma unroll
  for (int i = 0; i < 4; ++i)
#pragma unroll
    for (int j = 0; j < 4; ++j) acc[i][j] = (f32x4){0.f, 0.f, 0.f, 0.f};

  for (int kt = 0; kt < 1024; kt += 32) {
    stage_tile(A, row0, kt, As, tid);
    stage_tile(Be, col0, kt, Bs, tid);
    __syncthreads();
    frag8 a[4], b[4];
#pragma unroll
    for (int i = 0; i < 4; ++i) {
      int r = wm * 64 + i * 16 + lr;
      a[i] = *(const frag8*)&As[lds_slot(r, q) * 8];
    }
#pragma unroll
    for (int j = 0; j < 4; ++j) {
      int r = wn * 64 + j * 16 + lr;
      b[j] = *(const frag8*)&Bs[lds_slot(r, q) * 8];
    }
#pragma unroll
    for (int i = 0; i < 4; ++i)
#pragma unroll
      for (int j = 0; j < 4; ++j)
        acc[i][j] = __builtin_amdgcn_mfma_f32_16x16x32_bf16(a[i], b[j], acc[i][j], 0, 0, 0);
    __syncthreads();
  }
#pragma unroll
  for (int i = 0; i < 4; ++i)
#pragma unroll
    for (int j = 0; j < 4; ++j)
#pragma unroll
      for (int r = 0; r < 4; ++r) {
        int m = row0 + wm * 64 + i * 16 + q * 4 + r;
        int n = col0 + wn * 64 + j * 16 + lr;
        Y[(size_t)m * 1024 + n] = f2bf(acc[i][j][r]);
      }
}

// ---------------- final combine: out[t] = w0*Y[j0] + w1*Y[j1] + g*Y[8192+t] ----
__global__ void combine_kernel(const unsigned short* __restrict__ Y,
                               const int* __restrict__ inv, const float* __restrict__ tw,
                               const float* __restrict__ g, float* __restrict__ out) {
  int t = blockIdx.x;
  int c = threadIdx.x;                           // 256 threads * 4 elems
  int j0 = inv[2 * t], j1 = inv[2 * t + 1];
  float w0 = tw[2 * t], w1 = tw[2 * t + 1], gg = g[t];
  ushort4 a = ((const ushort4*)(Y + (size_t)j0 * 1024))[c];
  ushort4 b = ((const ushort4*)(Y + (size_t)j1 * 1024))[c];
  ushort4 s = ((const ushort4*)(Y + (size_t)(8192 + t) * 1024))[c];
  float4 o;
  o.x = w0 * bf2f(a.x) + w1 * bf2f(b.x) + gg * bf2f(s.x);
  o.y = w0 * bf2f(a.y) + w1 * bf2f(b.y) + gg * bf2f(s.y);
  o.z = w0 * bf2f(a.z) + w1 * bf2f(b.z) + gg * bf2f(s.z);
  o.w = w0 * bf2f(a.w) + w1 * bf2f(b.w) + gg * bf2f(s.w);
  ((float4*)(out + (size_t)t * 1024))[c] = o;
}

extern "C" void kernel_launch(void* const* d_in, const int* in_sizes, int n_in,
                              void* d_out, int out_size, void* d_ws, size_t ws_size,
                              hipStream_t stream) {
  (void)in_sizes; (void)n_in; (void)out_size; (void)ws_size;
  const float* hidden  = (const float*)d_in[0];
  const float* topk_w  = (const float*)d_in[1];
  const float* w_gate  = (const float*)d_in[2];
  const float* w_up    = (const float*)d_in[3];
  const float* w_down  = (const float*)d_in[4];
  const float* sw_gate = (const float*)d_in[5];
  const float* sw_up   = (const float*)d_in[6];
  const float* sw_down = (const float*)d_in[7];
  const float* sgw     = (const float*)d_in[8];
  const int*   topk_i  = (const int*)d_in[9];
  float* out = (float*)d_out;

  char* p = (char*)d_ws;
  auto alloc = [&](size_t bytes) {
    char* r = p;
    p += (bytes + 255) & ~(size_t)255;
    return r;
  };
  unsigned short* Wg_all = (unsigned short*)alloc((size_t)9 * 1048576 * 2);  // [9][1024][1024]
  unsigned short* Wu_all = (unsigned short*)alloc((size_t)9 * 1048576 * 2);
  unsigned short* Wd_all = (unsigned short*)alloc((size_t)9 * 1048576 * 2);
  unsigned short* Xall   = (unsigned short*)alloc((size_t)MROWS * 1024 * 2); // also reused as Y
  unsigned short* Hall   = (unsigned short*)alloc((size_t)MROWS * 1024 * 2);
  int*   cnt    = (int*)alloc(NE * 4);
  int*   rowdst = (int*)alloc((size_t)TTOK * KTOP * 4);
  int*   inv    = (int*)alloc((size_t)TTOK * KTOP * 4);
  float* gbuf   = (float*)alloc((size_t)TTOK * 4);
  unsigned short* Yall = Xall;   // Xall is dead after gemm1; alias to save ws

  hipMemsetAsync(cnt, 0, NE * 4, stream);

  perm_kernel<<<TTOK * KTOP / 256, 256, 0, stream>>>(topk_i, cnt, rowdst, inv);
  pack_kernel<<<MROWS, 256, 0, stream>>>(hidden, rowdst, Xall);
  transw_kernel<<<dim3(32, 32, 27), dim3(32, 8), 0, stream>>>(
      w_gate, w_up, w_down, sw_gate, sw_up, sw_down, Wg_all, Wu_all, Wd_all);
  gate_kernel<<<TTOK / 4, 256, 0, stream>>>(hidden, sgw, gbuf);

  gemm1_kernel<<<dim3(8, 96), 256, 0, stream>>>(Xall, Wg_all, Wu_all, Hall);
  gemm2_kernel<<<dim3(8, 96), 256, 0, stream>>>(Hall, Wd_all, Yall);
  combine_kernel<<<TTOK, 256, 0, stream>>>(Yall, inv, topk_w, gbuf, out);
}